// Round 2
// baseline (250.126 us; speedup 1.0000x reference)
//
#include <hip/hip_runtime.h>
#include <hip/hip_bf16.h>

#define SEQ   512
#define BATCH 256
#define ZD    64

typedef float vfloat4 __attribute__((ext_vector_type(4)));

__device__ __forceinline__ float lane_bcastf(float v, int i) {
  return __int_as_float(__builtin_amdgcn_readlane(__float_as_int(v), i));
}
__device__ __forceinline__ int lane_bcasti(int v, int i) {
  return __builtin_amdgcn_readlane(v, i);
}

// 64 distinct scalar names t00..t77 (two octal digits). The literal 0##n is
// an OCTAL constant equal to the linear index: t45 <-> 045 = 4*8+5 = 37.
#define REP8(M,p)  M(p##0) M(p##1) M(p##2) M(p##3) M(p##4) M(p##5) M(p##6) M(p##7)
#define REP64(M)   REP8(M,0) REP8(M,1) REP8(M,2) REP8(M,3) \
                   REP8(M,4) REP8(M,5) REP8(M,6) REP8(M,7)

#define TDECL(n)  float t##n;
#define TLOADF(n) t##n = Trp[0##n];          // T[lane][i], i = 0##n
#define TLOADB(n) t##n = Tcp[(0##n) * ZD];   // T[j][lane], j = 0##n
// Accumulate into 4 chains (constant index -> SROA keeps acc in registers).
#define TFMA(n)   acc[(0##n) & 3] = fmaf(lane_bcastf(vbc, 0##n), t##n, acc[(0##n) & 3]);
// Opaque register pin: named SSA scalars (NOT array elements -> no alloca).
// After this, LICM cannot re-sink the loads into the loop (rounds 3/4 failure).
#define TPIN(p)   asm volatile("" : "+v"(t##p##0), "+v"(t##p##1), "+v"(t##p##2), \
                                    "+v"(t##p##3), "+v"(t##p##4), "+v"(t##p##5), \
                                    "+v"(t##p##6), "+v"(t##p##7));
#define TPIN_ALL  TPIN(0) TPIN(1) TPIN(2) TPIN(3) TPIN(4) TPIN(5) TPIN(6) TPIN(7)

// One wave (64 lanes = 64 z-states) per chain; blocks 0..255 forward,
// 256..511 backward. No LDS, no barriers: shortest per-step critical path.
//
// Round 6: vmcnt-FIFO fix. vmcnt retires in ISSUE ORDER, so the old fwd loop
// (load e_t ... wait(e_t) ... store) had outstanding [store a_{t-1}, load e_t]
// at the wait -> compiler forced s_waitcnt vmcnt(0) -> drained the previous
// HBM store EVERY step, and e_t had only ~268 cyc slack (L3 ~450+). Fwd now
// prefetches e_{t+1} via a SHIFTED x register set (xvn[w] lane l = x[64w+l+1])
// so each iter issues its load BEFORE its store; the wait becomes vmcnt(2)
// with ~2 iterations (~540 cyc) of load slack. Bwd already had this shape.
// NT stores keep the 64MB output stream from evicting the 2.56MB emit table
// out of each XCD's 4MB L2.
__global__ __launch_bounds__(64, 1) void hmm_chains(
    const int*   __restrict__ inp,    // [SEQ, BATCH]
    const float* __restrict__ T,      // [ZD, ZD] row-major
    const float* __restrict__ pi,     // [ZD]
    const float* __restrict__ emit,   // [X, ZD]
    float* __restrict__ out_alpha,    // [SEQ, BATCH, ZD] fp32
    float* __restrict__ out_beta)     // [SEQ, BATCH, ZD] fp32
{
  const int lane = threadIdx.x;
  const int blk  = blockIdx.x;
  const bool fwd = (blk < BATCH);
  const int b    = fwd ? blk : blk - BATCH;

  REP64(TDECL)

  if (fwd) {
    // Shifted x registers: xvn[w] lane l = x[min(64w+l+1, 511)].
    // In-iter prefetch index x[t+1] is then a single readlane, no w-boundary.
    int xvn[8];
    #pragma unroll
    for (int w = 0; w < 8; ++w) {
      int li = w * 64 + lane + 1;
      if (li > SEQ - 1) li = SEQ - 1;        // t=511 prefetch: harmless re-load
      xvn[w] = inp[li * BATCH + b];
    }

    // alpha_t[l] = e_t[l] * sum_i alpha_{t-1}[i] * T[l][i]
    const float* Trp = T + lane * ZD;
    REP64(TLOADF)
    TPIN_ALL

    const int x0 = inp[b];                   // x[0], uniform scalar load
    float alpha = emit[x0 * ZD + lane] * pi[lane];
    float* op = out_alpha + (size_t)b * ZD + lane;

    // Prologue: issue load e_1 BEFORE storing alpha_0 (keeps loads older
    // than stores in the vmcnt FIFO from the very start).
    const int x1 = lane_bcasti(xvn[0], 0);
    float e_cur = emit[x1 * ZD + lane];      // e_1
    __builtin_nontemporal_store(alpha, op);
    op += BATCH * ZD;

    #pragma unroll
    for (int w = 0; w < 8; ++w) {
      const int xnw = xvn[w];
      #pragma unroll 1                 // keep body (~1.2 KB) inside L1I
      for (int idx = (w == 0) ? 1 : 0; idx < 64; ++idx) {
        const int   xt1  = lane_bcasti(xnw, idx);   // x[t+1] (uniform)
        const float e_pf = emit[xt1 * ZD + lane];   // issued FIRST, used next iter
        float acc[4] = {0.f, 0.f, 0.f, 0.f};
        const float vbc = alpha;
        REP64(TFMA)                               // 64 readlane + 64 fma
        alpha = e_cur * ((acc[0] + acc[1]) + (acc[2] + acc[3]));  // vmcnt(2) here
        __builtin_nontemporal_store(alpha, op);
        op += BATCH * ZD;
        e_cur = e_pf;
      }
    }
  } else {
    // beta_t[l] = sum_j (e_{t+1}[j]*beta_{t+1}[j]) * T[j][l]
    // Whole x-sequence in 8 lane-indexed VGPRs: xv[w] lane l = x[64w + l].
    int xv[8];
    #pragma unroll
    for (int w = 0; w < 8; ++w)
      xv[w] = inp[(w * 64 + lane) * BATCH + b];

    const float* Tcp = T + lane;
    REP64(TLOADB)
    TPIN_ALL

    float beta = 1.0f;
    float* op = out_beta + ((size_t)(SEQ - 1) * BATCH + b) * ZD + lane;
    __builtin_nontemporal_store(beta, op);
    op -= BATCH * ZD;

    const int xL = lane_bcasti(xv[7], 63);
    float e_next = emit[xL * ZD + lane];          // e_{511}, consumed at t=510

    #pragma unroll
    for (int w = 7; w >= 0; --w) {
      const int xvw = xv[w];
      #pragma unroll 1
      for (int idx = (w == 7) ? 62 : 63; idx >= 0; --idx) {
        const int   xt   = lane_bcasti(xvw, idx); // x_t, e for next iteration
        const float e_pf = emit[xt * ZD + lane];  // issued FIRST, used next iter
        const float vbc  = e_next * beta;         // g[j] broadcast source
        float acc[4] = {0.f, 0.f, 0.f, 0.f};
        REP64(TFMA)
        beta = (acc[0] + acc[1]) + (acc[2] + acc[3]);
        __builtin_nontemporal_store(beta, op);
        op -= BATCH * ZD;
        e_next = e_pf;
      }
    }
  }
}

// posterior[t,b,z] = alpha*beta / sum_z(alpha*beta). 8 z per lane (2x vfloat4),
// 8 lanes per (t,b) row, xor-shuffle reduction within the 8-lane group.
// Streamed once -> nontemporal loads/stores (skip L2 allocate).
// NOTE: __builtin_nontemporal_* requires a clang vector type, not HIP's
// float4 class -> vfloat4 (ext_vector_type).
__global__ __launch_bounds__(256) void posterior_k(
    const float* __restrict__ a,
    const float* __restrict__ bt,
    float*       __restrict__ p)
{
  const int tid = blockIdx.x * 256 + threadIdx.x;
  const size_t base = (size_t)tid * 8;

  const vfloat4 va0 = __builtin_nontemporal_load(reinterpret_cast<const vfloat4*>(a  + base));
  const vfloat4 va1 = __builtin_nontemporal_load(reinterpret_cast<const vfloat4*>(a  + base + 4));
  const vfloat4 vb0 = __builtin_nontemporal_load(reinterpret_cast<const vfloat4*>(bt + base));
  const vfloat4 vb1 = __builtin_nontemporal_load(reinterpret_cast<const vfloat4*>(bt + base + 4));

  const float p0 = va0.x * vb0.x;
  const float p1 = va0.y * vb0.y;
  const float p2 = va0.z * vb0.z;
  const float p3 = va0.w * vb0.w;
  const float p4 = va1.x * vb1.x;
  const float p5 = va1.y * vb1.y;
  const float p6 = va1.z * vb1.z;
  const float p7 = va1.w * vb1.w;

  float s = ((p0 + p1) + (p2 + p3)) + ((p4 + p5) + (p6 + p7));
  s += __shfl_xor(s, 1);
  s += __shfl_xor(s, 2);
  s += __shfl_xor(s, 4);
  const float inv = 1.0f / s;

  vfloat4 o0, o1;
  o0.x = p0 * inv; o0.y = p1 * inv; o0.z = p2 * inv; o0.w = p3 * inv;
  o1.x = p4 * inv; o1.y = p5 * inv; o1.z = p6 * inv; o1.w = p7 * inv;
  __builtin_nontemporal_store(o0, reinterpret_cast<vfloat4*>(p + base));
  __builtin_nontemporal_store(o1, reinterpret_cast<vfloat4*>(p + base + 4));
}

extern "C" void kernel_launch(void* const* d_in, const int* in_sizes, int n_in,
                              void* d_out, int out_size, void* d_ws, size_t ws_size,
                              hipStream_t stream) {
  const int*   inp  = (const int*)  d_in[0];
  const float* T    = (const float*)d_in[1];
  const float* pi   = (const float*)d_in[2];
  const float* emit = (const float*)d_in[3];

  float* out = (float*)d_out;
  const size_t N = (size_t)SEQ * BATCH * ZD;   // 8388608 per output
  float* out_alpha = out;
  float* out_beta  = out + N;
  float* out_post  = out + 2 * N;

  hipLaunchKernelGGL(hmm_chains, dim3(2 * BATCH), dim3(64), 0, stream,
                     inp, T, pi, emit, out_alpha, out_beta);

  hipLaunchKernelGGL(posterior_k, dim3((unsigned)(N / 2048)), dim3(256), 0, stream,
                     out_alpha, out_beta, out_post);
}